// Round 12
// baseline (4129.967 us; speedup 1.0000x reference)
//
#include <hip/hip_runtime.h>
#include <math.h>

// Problem constants
constexpr int BB   = 4;
constexpr int TT   = 1024;
constexpr int DD   = 1024;
constexpr int LL   = 3;
constexpr int HH   = 4;
constexpr int HS   = 256;
constexpr int D4   = 4096;
constexpr int VOC  = 50257;
constexpr int BT   = BB * TT;  // 4096
constexpr int LDT  = 40;       // LDS row stride (32 + 8 pad) in bf16 elems

typedef unsigned short u16;
typedef unsigned int   u32;
typedef __attribute__((ext_vector_type(8))) short bf16x8;
typedef __attribute__((ext_vector_type(4))) float f32x4;
// 4-byte-aligned float4 for loads from odd-ld fp32 matrices (lm_W): well-defined
// at 4B alignment; backend emits dwordx4 under unaligned-access-mode, else splits.
typedef __attribute__((ext_vector_type(4), aligned(4))) float f32x4u;

__device__ inline float b2f(u16 u) {
    union { u32 i; float f; } v; v.i = (u32)u << 16; return v.f;
}
__device__ inline u16 f2b(float f) {   // round-to-nearest-even
    u32 u = __float_as_uint(f);
    u += 0x7fffu + ((u >> 16) & 1u);
    return (u16)(u >> 16);
}

enum { EPI_NONE = 0, EPI_SCORE = 1, EPI_BIAS = 2, EPI_BIAS_RELU = 3, EPI_BIAS_RES = 4 };
enum { B_BF16T = 0, B_F32N = 1 };

// ---------------------------------------------------------------------------
// bf16 MFMA GEMM:  C[z] = epi( A[z] (MxK bf16, row-major)  *  B[z] )
//   BMODE=B_BF16T: Bsrc is bf16 NxK (k-contiguous), staged directly.
//   BMODE=B_F32N : Bsrc is fp32 KxN (row-major original weights), converted
//                  + transposed into the [n][k] LDS tile on the fly.
// 128x128 tile, BK=32, 256 thr = 4 waves, each wave 64x64 via 4x4 frags of
// mfma_f32_16x16x32_bf16. Batch: z -> zq=z/div, zr=z%div; off = zq*s1+zr*s2.
// CT: write bf16 C transposed (C[col][row]).
// TRIK: truncate K-loop at bm+128 (AV GEMM: att[t][s]=0 for s>t exactly).
// EPI_SCORE: tiles fully above the diagonal short-circuit to -inf writes.
// ---------------------------------------------------------------------------
template <int EPI, int BMODE, bool WF32, bool WB16, bool CT, bool NGUARD, bool SWAPXY, bool TRIK>
__global__ __launch_bounds__(256)
void bgemm_k(const u16* __restrict__ A, const void* __restrict__ Bsrc,
             float* Cf, u16* Cb,
             const float* __restrict__ bias, const float* Res,
             int M, int N, int K, int lda, int ldb, int ldc,
             int div, long sA1, long sA2, long sB1, long sB2, long sC1, long sC2,
             float scale)
{
    __shared__ __align__(16) u16 As[128 * LDT];
    __shared__ __align__(16) u16 Bs[128 * LDT];

    const int z = blockIdx.z, zq = z / div, zr = z % div;
    A += (size_t)zq * sA1 + (size_t)zr * sA2;
    const size_t offB = (size_t)zq * sB1 + (size_t)zr * sB2;
    const size_t offC = (size_t)zq * sC1 + (size_t)zr * sC2;

    const int bm = (SWAPXY ? blockIdx.x : blockIdx.y) * 128;
    const int bn = (SWAPXY ? blockIdx.y : blockIdx.x) * 128;
    const int tid  = threadIdx.x;
    const int lane = tid & 63;
    const int w    = tid >> 6;
    const int wr   = (w >> 1) * 64, wc = (w & 1) * 64;
    const int fr   = lane & 15;          // frag row (A) / col (B, D)
    const int fk   = (lane >> 4) * 8;    // frag k offset

    // Fully-masked score tile: min col (bn) > max row (bm+127) -> all -inf.
    if (EPI == EPI_SCORE && bn >= bm + 128) {
#pragma unroll
        for (int i = 0; i < 4; ++i)
#pragma unroll
            for (int j = 0; j < 4; ++j)
#pragma unroll
                for (int r = 0; r < 4; ++r) {
                    const int row = bm + wr + i * 16 + (lane >> 4) * 4 + r;
                    const int col = bn + wc + j * 16 + fr;
                    Cb[offC + (size_t)row * ldc + col] = (u16)0xFF80;
                }
        return;
    }

    // A staging: 512 chunks of 8 bf16; 2 per thread. chunk c -> row c>>2, k (c&3)*8
    const int ma = tid >> 2,         ka = (tid & 3) * 8;
    const int mb = (tid + 256) >> 2, kb = (tid & 3) * 8;

    f32x4 acc[4][4];
#pragma unroll
    for (int i = 0; i < 4; ++i)
#pragma unroll
        for (int j = 0; j < 4; ++j) acc[i][j] = (f32x4){0.f, 0.f, 0.f, 0.f};

    const int Kend = TRIK ? (bm + 128 < K ? bm + 128 : K) : K;

    for (int k0 = 0; k0 < Kend; k0 += 32) {
        *(bf16x8*)(As + ma * LDT + ka) = *(const bf16x8*)(A + (size_t)(bm + ma) * lda + k0 + ka);
        *(bf16x8*)(As + mb * LDT + kb) = *(const bf16x8*)(A + (size_t)(bm + mb) * lda + k0 + kb);

        if (BMODE == B_BF16T) {
            const u16* Bt = (const u16*)Bsrc + offB;
            *(bf16x8*)(Bs + ma * LDT + ka) = *(const bf16x8*)(Bt + (size_t)(bn + ma) * ldb + k0 + ka);
            *(bf16x8*)(Bs + mb * LDT + kb) = *(const bf16x8*)(Bt + (size_t)(bn + mb) * ldb + k0 + kb);
        } else {
            const float* Bf = (const float*)Bsrc + offB;
            const bool fullN = !NGUARD || (bn + 128 <= N);
            // 512 units: unit u -> k-pair kp = u>>5 (k = 2*kp, 2*kp+1), n4 = (u&31)*4
#pragma unroll
            for (int it = 0; it < 2; ++it) {
                const int u  = tid + it * 256;
                const int kp = u >> 5;
                const int n4 = (u & 31) * 4;
                const float* p0 = Bf + (size_t)(k0 + 2 * kp) * ldb + bn + n4;
                const float* p1 = p0 + ldb;
                float v0[4], v1[4];
                if (fullN) {
                    const f32x4u a0 = *(const f32x4u*)p0;   // 4B-aligned-safe vector load
                    const f32x4u a1 = *(const f32x4u*)p1;
#pragma unroll
                    for (int c = 0; c < 4; ++c) { v0[c] = a0[c]; v1[c] = a1[c]; }
                } else {
#pragma unroll
                    for (int c = 0; c < 4; ++c) {
                        const bool ok = (bn + n4 + c) < N;
                        v0[c] = ok ? p0[c] : 0.f;
                        v1[c] = ok ? p1[c] : 0.f;
                    }
                }
#pragma unroll
                for (int c = 0; c < 4; ++c) {
                    const u32 pk = (u32)f2b(v0[c]) | ((u32)f2b(v1[c]) << 16);
                    *(u32*)(Bs + (size_t)(n4 + c) * LDT + 2 * kp) = pk;
                }
            }
        }
        __syncthreads();

        bf16x8 a[4], b[4];
#pragma unroll
        for (int i = 0; i < 4; ++i)
            a[i] = *(const bf16x8*)(As + (wr + i * 16 + fr) * LDT + fk);
#pragma unroll
        for (int j = 0; j < 4; ++j)
            b[j] = *(const bf16x8*)(Bs + (wc + j * 16 + fr) * LDT + fk);
#pragma unroll
        for (int i = 0; i < 4; ++i)
#pragma unroll
            for (int j = 0; j < 4; ++j)
                acc[i][j] = __builtin_amdgcn_mfma_f32_16x16x32_bf16(a[i], b[j], acc[i][j], 0, 0, 0);
        __syncthreads();
    }

    // epilogue (D mapping: col=lane&15, row=(lane>>4)*4+reg — m89/m91)
#pragma unroll
    for (int i = 0; i < 4; ++i)
#pragma unroll
        for (int j = 0; j < 4; ++j)
#pragma unroll
            for (int r = 0; r < 4; ++r) {
                const int row = bm + wr + i * 16 + (lane >> 4) * 4 + r;
                const int col = bn + wc + j * 16 + fr;
                if (NGUARD && col >= N) continue;
                float x = acc[i][j][r];
                if (EPI == EPI_SCORE) x *= scale;
                if (EPI == EPI_BIAS || EPI == EPI_BIAS_RELU || EPI == EPI_BIAS_RES)
                    x += bias[col];
                if (EPI == EPI_BIAS_RELU) x = fmaxf(x, 0.f);
                if (EPI == EPI_BIAS_RES) x += Res[offC + (size_t)row * ldc + col];
                if (WF32) Cf[offC + (size_t)row * ldc + col] = x;
                if (WB16) {
                    const u16 hv = (EPI == EPI_SCORE && col > row) ? (u16)0xFF80 : f2b(x);
                    if (CT) Cb[offC + (size_t)col * ldc + row] = hv;
                    else    Cb[offC + (size_t)row * ldc + col] = hv;
                }
            }
}

// ---------------------------------------------------------------------------
// x = tok_emb[idx] + pos_emb, dual write fp32 + bf16
// ---------------------------------------------------------------------------
__global__ __launch_bounds__(256)
void embed_k(const int* __restrict__ idx, const float* __restrict__ tok,
             const float* __restrict__ pos, float* __restrict__ X, u16* __restrict__ Xb)
{
    const int bt = blockIdx.x;
    const int t  = bt & (TT - 1);
    const int id = idx[bt];
    const int i  = threadIdx.x;
    const float4 a = ((const float4*)(tok + (size_t)id * DD))[i];
    const float4 b = ((const float4*)(pos + (size_t)t * DD))[i];
    const float4 o = make_float4(a.x + b.x, a.y + b.y, a.z + b.z, a.w + b.w);
    ((float4*)(X + (size_t)bt * DD))[i] = o;
    ushort4 h;
    h.x = f2b(o.x); h.y = f2b(o.y); h.z = f2b(o.z); h.w = f2b(o.w);
    ((ushort4*)(Xb + (size_t)bt * DD))[i] = h;
}

// ---------------------------------------------------------------------------
// Column softmax over the QUERY axis on bf16 scores, in place.
// att[t][s] = exp(w[t][s]) / sum_t' exp(w[t'][s]); exp(-inf)=0 handles mask.
// ---------------------------------------------------------------------------
__global__ __launch_bounds__(256)
void colsoftmax_k(u16* __restrict__ W)
{
    const int bh = blockIdx.x;
    const int c = threadIdx.x & 63;
    const int g = threadIdx.x >> 6;
    const int s = blockIdx.y * 64 + c;
    u16* Wp = W + (size_t)bh * TT * TT;

    const int t0 = g * (TT / 4), t1 = t0 + TT / 4;
    float sum = 0.f;
    for (int t = t0; t < t1; ++t)
        sum += __expf(b2f(Wp[(size_t)t * TT + s]));

    __shared__ float red[4][64];
    red[g][c] = sum;
    __syncthreads();
    const float r = 1.f / (red[0][c] + red[1][c] + red[2][c] + red[3][c]);

    for (int t = t0; t < t1; ++t) {
        const size_t o = (size_t)t * TT + s;
        Wp[o] = f2b(__expf(b2f(Wp[o])) * r);
    }
}

// ---------------------------------------------------------------------------
extern "C" void kernel_launch(void* const* d_in, const int* in_sizes, int n_in,
                              void* d_out, int out_size, void* d_ws, size_t ws_size,
                              hipStream_t stream)
{
    const int*   idx  = (const int*)d_in[0];
    const float* tok  = (const float*)d_in[1];
    const float* pos  = (const float*)d_in[2];
    const float* Wq   = (const float*)d_in[3];
    const float* Wk   = (const float*)d_in[4];
    const float* Wv   = (const float*)d_in[5];
    const float* Wpj  = (const float*)d_in[6];
    const float* bpj  = (const float*)d_in[7];
    const float* W1   = (const float*)d_in[8];
    const float* b1   = (const float*)d_in[9];
    const float* W2   = (const float*)d_in[10];
    const float* b2   = (const float*)d_in[11];
    const float* lmW  = (const float*)d_in[12];
    const float* lmb  = (const float*)d_in[13];
    float* out = (float*)d_out;

    // ---- workspace layout (~88 MB) ----
    char* p = (char*)d_ws;
    auto alloc = [&](size_t bytes) { char* q = p; p += (bytes + 255) & ~(size_t)255; return q; };
    float* X   = (float*)alloc((size_t)BT * DD * 4);          // fp32 residual stream
    u16* Xb    = (u16*)alloc((size_t)BT * DD * 2);            // bf16 mirror
    u16* Qb    = (u16*)alloc((size_t)BB * HH * TT * HS * 2);  // [b][h][t][e]
    u16* Kbb   = (u16*)alloc((size_t)BB * HH * TT * HS * 2);  // [b][h][t][e]
    u16* Vt    = (u16*)alloc((size_t)BB * HH * HS * TT * 2);  // [b][h][e][t]
    u16* Ob    = (u16*)alloc((size_t)BT * DD * 2);            // [b][t][h*HS+e]
    u16* Sb    = (u16*)alloc((size_t)BB * HH * TT * TT * 2);  // scores / MLP hidden

    const float scale = 0.03125f;  // D^-0.5 = 1/32

    embed_k<<<dim3(BT), 256, 0, stream>>>(idx, tok, pos, X, Xb);

    const long sQ1 = (long)HH * TT * HS, sQ2 = (long)TT * HS;   // Q/K [b][h]
    const long sV1 = (long)HH * HS * TT, sV2 = (long)HS * TT;   // Vt  [b][h]
    const long sS1 = (long)HH * TT * TT, sS2 = (long)TT * TT;   // scores [b][h]
    const long sWh = (long)DD * HS;                             // per-head weight (fp32 elems)

    for (int l = 0; l < LL; ++l) {
        // Q = X @ Wq[l,h]  (per b,h: 1024x256, K=1024); B fp32 [d][e] on-the-fly
        bgemm_k<EPI_NONE, B_F32N, false, true, false, false, false, false><<<dim3(2, 8, BB * HH), 256, 0, stream>>>(
            Xb, Wq + (size_t)l * HH * DD * HS, nullptr, Qb, nullptr, nullptr,
            TT, HS, DD, DD, HS, HS,
            HH, (long)TT * DD, 0, 0, sWh, sQ1, sQ2, 0.f);
        // K = X @ Wk[l,h]
        bgemm_k<EPI_NONE, B_F32N, false, true, false, false, false, false><<<dim3(2, 8, BB * HH), 256, 0, stream>>>(
            Xb, Wk + (size_t)l * HH * DD * HS, nullptr, Kbb, nullptr, nullptr,
            TT, HS, DD, DD, HS, HS,
            HH, (long)TT * DD, 0, 0, sWh, sQ1, sQ2, 0.f);
        // V = X @ Wv[l,h], stored transposed [e][t]
        bgemm_k<EPI_NONE, B_F32N, false, true, true, false, false, false><<<dim3(2, 8, BB * HH), 256, 0, stream>>>(
            Xb, Wv + (size_t)l * HH * DD * HS, nullptr, Vt, nullptr, nullptr,
            TT, HS, DD, DD, HS, TT,
            HH, (long)TT * DD, 0, 0, sWh, sV1, sV2, 0.f);

        // scores = (Q @ K^T) * scale, mask col>row -> -inf (bf16); above-diag tiles short-circuit
        bgemm_k<EPI_SCORE, B_BF16T, false, true, false, false, false, false><<<dim3(8, 8, BB * HH), 256, 0, stream>>>(
            Qb, Kbb, nullptr, Sb, nullptr, nullptr,
            TT, TT, HS, HS, HS, TT,
            HH, sQ1, sQ2, sQ1, sQ2, sS1, sS2, scale);

        // softmax over query axis (column softmax), in place
        colsoftmax_k<<<dim3(BB * HH, TT / 64), 256, 0, stream>>>(Sb);

        // O = att @ V  -> [b][t][h*HS+e]; att[t][s]=0 for s>t -> truncate K at bm+128
        bgemm_k<EPI_NONE, B_BF16T, false, true, false, false, false, true><<<dim3(2, 8, BB * HH), 256, 0, stream>>>(
            Sb, Vt, nullptr, Ob, nullptr, nullptr,
            TT, HS, TT, TT, TT, DD,
            HH, sS1, sS2, sV1, sV2, (long)TT * DD, (long)HS, 0.f);

        // x = x + O @ Wproj + bproj   (fp32 X + bf16 Xb dual write)
        bgemm_k<EPI_BIAS_RES, B_F32N, true, true, false, false, false, false><<<dim3(8, 32, 1), 256, 0, stream>>>(
            Ob, Wpj + (size_t)l * DD * DD, X, Xb, bpj + (size_t)l * DD, X,
            BT, DD, DD, DD, DD, DD,
            1, 0, 0, 0, 0, 0, 0, 0.f);

        // h1 = relu(x @ W1 + b1)  (bf16, into Sb region)
        bgemm_k<EPI_BIAS_RELU, B_F32N, false, true, false, false, false, false><<<dim3(32, 32, 1), 256, 0, stream>>>(
            Xb, W1 + (size_t)l * DD * D4, nullptr, Sb, b1 + (size_t)l * D4, nullptr,
            BT, D4, DD, DD, D4, D4,
            1, 0, 0, 0, 0, 0, 0, 0.f);

        // x = x + h1 @ W2 + b2
        bgemm_k<EPI_BIAS_RES, B_F32N, true, true, false, false, false, false><<<dim3(8, 32, 1), 256, 0, stream>>>(
            Sb, W2 + (size_t)l * D4 * DD, X, Xb, b2 + (size_t)l * DD, X,
            BT, DD, D4, D4, DD, DD,
            1, 0, 0, 0, 0, 0, 0, 0.f);
    }

    // logits = x @ lm_W + lm_b  (fp32 out; N=50257 guarded; SWAPXY for L2 reuse of W strip)
    bgemm_k<EPI_BIAS, B_F32N, true, false, false, true, true, false><<<dim3(32, (VOC + 127) / 128, 1), 256, 0, stream>>>(
        Xb, lmW, out, nullptr, lmb, nullptr,
        BT, VOC, DD, DD, VOC, VOC,
        1, 0, 0, 0, 0, 0, 0, 0.f);
}